// Round 28
// baseline (34.268 us; speedup 1.0000x reference)
//
#include <hip/hip_runtime.h>

// SphericalVectorPool on MI355X — R25 with occupancy-granularity fix.
// R27 post-mortem: 6 mechanisms excluded; remaining source-visible term is
// the grid tail: R25's 10.88KB LDS + 1KB red -> 13 blocks/CU -> 4096 blocks
// run in 1.23 passes (768-block tail at low utilization). This round: tile
// stride 136->128 hw (bank-verified: writes span 256B = 2 lanes/bank = free
// (m136); reads are 4-addr broadcast b128) and wave1 acc parked in its own
// dead LDS region -> 10.24KB total -> 15 blocks/CU -> 1.07 passes.
// E-gen, K-permuted layout, MFMA, D-map epilogue byte-identical to R25.

constexpr int NR    = 16;
constexpr int BATCH = 2;
constexpr int NSRC  = 2048;
constexpr int MOUT  = 2048;

typedef __fp16 h2 __attribute__((ext_vector_type(2)));
typedef _Float16 f16x8 __attribute__((ext_vector_type(8)));
typedef float f32x4 __attribute__((ext_vector_type(4)));

__global__ __launch_bounds__(128, 1) void svp_kernel(
    const float* __restrict__ f,       // [B,N]
    const float* __restrict__ coords,  // [B,N,3]
    const float* __restrict__ outc,    // [B,M,3]
    const float* __restrict__ mu,      // [16]
    const float* __restrict__ rn,      // [16]
    const float* __restrict__ an0,     // [1]
    const float* __restrict__ an1,     // [1]
    float* __restrict__ out)           // [B,M,64]
{
    const int tid  = threadIdx.x;
    const int lane = tid & 63;
    const int w    = tid >> 6;                // wave in block: 0..1
    const int anchor = blockIdx.x;            // 0..4095
    const int b = anchor >> 11;
    const int col = lane & 15;
    const int grp = lane >> 4;

    // per-wave region: rows 0..15 = eT, 16..19 = wT; stride 128 hw (256B).
    // Banks: writes = 64 lanes x b32 spanning 256B -> 2 lanes/bank (free);
    // reads = b128 at 4 unique addrs x 16-lane broadcast (free).
    __shared__ __align__(16) unsigned short sm[2][20][128];
    unsigned short (* __restrict__ eT)[128] = sm[w];
    unsigned short (* __restrict__ wT)[128] = sm[w] + 16;

    const float NL2E = -1.44269504088896340736f;

    const float nm16 = mu[15] * NL2E;
    const float nm14 = mu[13] * NL2E;
    const float nm12 = mu[11] * NL2E;
    const float nm10 = mu[9]  * NL2E;

    const float dl15 = mu[14] - mu[15];
    const float dl13 = mu[12] - mu[13];
    const float dl11 = mu[10] - mu[11];
    const float dl9  = mu[8]  - mu[9];
    const h2 hD15 = __builtin_amdgcn_cvt_pkrtz(dl15, dl15);
    const h2 hD13 = __builtin_amdgcn_cvt_pkrtz(dl13, dl13);
    const h2 hD11 = __builtin_amdgcn_cvt_pkrtz(dl11, dl11);
    const h2 hD9  = __builtin_amdgcn_cvt_pkrtz(dl9,  dl9);

    // cubic Taylor of exp(-x)
    const h2 C3 = {(__fp16)(-1.0f / 6.0f), (__fp16)(-1.0f / 6.0f)};
    const h2 C2 = {(__fp16)0.5f,  (__fp16)0.5f};
    const h2 C1 = {(__fp16)-1.0f, (__fp16)-1.0f};
    const h2 C0 = {(__fp16)1.0f,  (__fp16)1.0f};

    const float Rx = outc[(size_t)anchor * 3 + 0];
    const float Ry = outc[(size_t)anchor * 3 + 1];
    const float Rz = outc[(size_t)anchor * 3 + 2];

    f32x4 acc = {0.f, 0.f, 0.f, 0.f};

    const float* cb = coords + (size_t)b * NSRC * 3;
    const float* fb = f + (size_t)b * NSRC;

    // K-permuted write position (R25-verified): lane owns local srcs (2t,2t+1)
    const int t = lane & 15;
    const int pos = (t < 8) ? (8 * (t >> 1) + 2 * (t & 1))
                            : (8 * ((t - 8) >> 1) + 4 + 2 * (t & 1));
    const int whw = 32 * (lane >> 4) + pos;
    const int rhw = 8 * grp;

    for (int i = 0; i < 8; ++i) {             // 8 iterations, 128 src each
        const int s0 = w * (NSRC / 2) + i * 128 + 2 * lane;  // lane: s0, s0+1
        const float2 c0 = *(const float2*)(cb + (size_t)s0 * 3);      // x0 y0
        const float2 c1 = *(const float2*)(cb + (size_t)s0 * 3 + 2);  // z0 x1
        const float2 c2 = *(const float2*)(cb + (size_t)s0 * 3 + 4);  // y1 z1
        const float2 f2 = *(const float2*)(fb + s0);

        const float dx0 = c0.x - Rx, dy0 = c0.y - Ry, dz0 = c1.x - Rz;
        const float dx1 = c1.y - Rx, dy1 = c2.x - Ry, dz1 = c2.y - Rz;

        const float sq0 = dx0 * dx0 + dy0 * dy0 + dz0 * dz0;
        const float sq1 = dx1 * dx1 + dy1 * dy1 + dz1 * dz1;
        const float ri0 = __builtin_amdgcn_rsqf(sq0);
        const float ri1 = __builtin_amdgcn_rsqf(sq1);
        const float d0 = sq0 * ri0, d1 = sq1 * ri1;
        const float t0 = f2.x * ri0, t1 = f2.y * ri1;

        const h2 dpk = __builtin_amdgcn_cvt_pkrtz(d0, d1);

        h2 ep[16];
        ep[15] = __builtin_amdgcn_cvt_pkrtz(
            __builtin_amdgcn_exp2f(d0 * nm16), __builtin_amdgcn_exp2f(d1 * nm16));
        ep[13] = __builtin_amdgcn_cvt_pkrtz(
            __builtin_amdgcn_exp2f(d0 * nm14), __builtin_amdgcn_exp2f(d1 * nm14));
        ep[11] = __builtin_amdgcn_cvt_pkrtz(
            __builtin_amdgcn_exp2f(d0 * nm12), __builtin_amdgcn_exp2f(d1 * nm12));
        ep[9]  = __builtin_amdgcn_cvt_pkrtz(
            __builtin_amdgcn_exp2f(d0 * nm10), __builtin_amdgcn_exp2f(d1 * nm10));

        ep[7] = ep[15] * ep[15];   // E8
        ep[6] = ep[13] * ep[13];   // E7
        ep[5] = ep[11] * ep[11];   // E6
        ep[4] = ep[9]  * ep[9];    // E5
        ep[3] = ep[7]  * ep[7];    // E4
        ep[2] = ep[5]  * ep[5];    // E3
        ep[1] = ep[3]  * ep[3];    // E2
        ep[0] = ep[1]  * ep[1];    // E1

#define ODD(K_ODD, K_EVEN, HD)                                            \
        {                                                                 \
            h2 x = dpk * (HD);                                            \
            h2 p = C0 + x * (C1 + x * (C2 + x * C3));                     \
            ep[K_ODD] = ep[K_EVEN] * p;                                   \
        }
        ODD(14, 15, hD15)   // E15 = E16 * corr
        ODD(12, 13, hD13)   // E13 = E14 * corr
        ODD(10, 11, hD11)   // E11 = E12 * corr
        ODD(8,  9,  hD9)    // E9  = E10 * corr
#undef ODD

        // LDS scatter: one b32 per row (2 sources)
#pragma unroll
        for (int k = 0; k < 16; ++k)
            *(unsigned*)&eT[k][whw] = __builtin_bit_cast(unsigned, ep[k]);
        *(unsigned*)&wT[0][whw] =
            __builtin_bit_cast(unsigned, __builtin_amdgcn_cvt_pkrtz(f2.x, f2.y));
        *(unsigned*)&wT[1][whw] =
            __builtin_bit_cast(unsigned, __builtin_amdgcn_cvt_pkrtz(t0 * dx0, t1 * dx1));
        *(unsigned*)&wT[2][whw] =
            __builtin_bit_cast(unsigned, __builtin_amdgcn_cvt_pkrtz(t0 * dy0, t1 * dy1));
        *(unsigned*)&wT[3][whw] =
            __builtin_bit_cast(unsigned, __builtin_amdgcn_cvt_pkrtz(t0 * dz0, t1 * dz1));

        // 4 MFMA chunks of 32 sources, b128 fragment reads
#pragma unroll
        for (int c = 0; c < 4; ++c) {
            const f16x8 av = *(const f16x8*)&eT[col][32 * c + rhw];
            const f16x8 bv = *(const f16x8*)&wT[col & 3][32 * c + rhw];
            acc = __builtin_amdgcn_mfma_f32_16x16x32_f16(av, bv, acc, 0, 0, 0);
        }
    }

    // cross-wave combine: wave1 parks acc in its own (now dead) LDS region
    if (w == 1) {
        f32x4* red = (f32x4*)&sm[1][0][0];
        red[lane] = acc;
    }
    __syncthreads();
    if (w == 0) {
        const f32x4* red = (const f32x4*)&sm[1][0][0];
        acc += red[lane];
        // D[row=4*grp+r][col]: col = component, row = k (m89-verified map)
        if (col < 4) {
            const float4 r4 = *(const float4*)&rn[4 * grp];
            const float an = (col == 0) ? an0[0] : an1[0];
            float4 o;
            o.x = acc[0] * r4.x * an;
            o.y = acc[1] * r4.y * an;
            o.z = acc[2] * r4.z * an;
            o.w = acc[3] * r4.w * an;
            *(float4*)&out[(size_t)anchor * 64 + col * 16 + 4 * grp] = o;
        }
    }
}

extern "C" void kernel_launch(void* const* d_in, const int* in_sizes, int n_in,
                              void* d_out, int out_size, void* d_ws, size_t ws_size,
                              hipStream_t stream) {
    const float* f      = (const float*)d_in[0];
    const float* coords = (const float*)d_in[1];
    const float* outc   = (const float*)d_in[2];
    const float* mu     = (const float*)d_in[3];
    const float* rn     = (const float*)d_in[4];
    const float* an0    = (const float*)d_in[5];
    const float* an1    = (const float*)d_in[6];
    float* out = (float*)d_out;

    const int anchors = BATCH * MOUT;              // 4096 blocks, 2 waves each
    svp_kernel<<<anchors, 128, 0, stream>>>(f, coords, outc, mu, rn, an0, an1, out);
}

// Round 29
// 24.193 us; speedup vs baseline: 1.4165x; 1.4165x over previous
//
#include <hip/hip_runtime.h>

// SphericalVectorPool on MI355X — R25 byte-identical + dead-LDS acc park.
// R28 post-mortem: stride 128 collapsed the fragment-read bank spread
// (row base ≡ bank 0 -> 16 lanes per 4-bank group = 2x b128 serialization,
// +10.7us). R25's stride 136 (68 dwords ≡ 4 mod 32 -> (col+grp)%8 uniform
// over the 8 aligned bank-groups) is the b128 read OPTIMUM — restored here.
// Only change vs R25: wave1's accumulator parks in its own dead LDS region
// (saves the 1KB red array): 11.9 -> 10.88 KB -> 15 blocks/CU -> grid runs
// in 1.07 passes instead of 1.23 (clean test of the tail hypothesis).

constexpr int NR    = 16;
constexpr int BATCH = 2;
constexpr int NSRC  = 2048;
constexpr int MOUT  = 2048;

typedef __fp16 h2 __attribute__((ext_vector_type(2)));
typedef _Float16 f16x8 __attribute__((ext_vector_type(8)));
typedef float f32x4 __attribute__((ext_vector_type(4)));

__global__ __launch_bounds__(128, 1) void svp_kernel(
    const float* __restrict__ f,       // [B,N]
    const float* __restrict__ coords,  // [B,N,3]
    const float* __restrict__ outc,    // [B,M,3]
    const float* __restrict__ mu,      // [16]
    const float* __restrict__ rn,      // [16]
    const float* __restrict__ an0,     // [1]
    const float* __restrict__ an1,     // [1]
    float* __restrict__ out)           // [B,M,64]
{
    const int tid  = threadIdx.x;
    const int lane = tid & 63;
    const int w    = tid >> 6;                // wave in block: 0..1
    const int anchor = blockIdx.x;            // 0..4095
    const int b = anchor >> 11;
    const int col = lane & 15;
    const int grp = lane >> 4;

    // per-wave region: rows 0..15 = eT, rows 16..19 = wT; stride 136 hw
    // (68 dwords ≡ 4 mod 32): fragment-read bank-groups = (col+grp)%8,
    // uniform 8 lanes/group = b128 read optimum (R28 proved 128 is 2x worse).
    __shared__ __align__(16) unsigned short sm[2][20][136];
    unsigned short (* __restrict__ eT)[136] = sm[w];
    unsigned short (* __restrict__ wT)[136] = sm[w] + 16;

    const float NL2E = -1.44269504088896340736f;

    const float nm16 = mu[15] * NL2E;
    const float nm14 = mu[13] * NL2E;
    const float nm12 = mu[11] * NL2E;
    const float nm10 = mu[9]  * NL2E;

    const float dl15 = mu[14] - mu[15];
    const float dl13 = mu[12] - mu[13];
    const float dl11 = mu[10] - mu[11];
    const float dl9  = mu[8]  - mu[9];
    const h2 hD15 = __builtin_amdgcn_cvt_pkrtz(dl15, dl15);
    const h2 hD13 = __builtin_amdgcn_cvt_pkrtz(dl13, dl13);
    const h2 hD11 = __builtin_amdgcn_cvt_pkrtz(dl11, dl11);
    const h2 hD9  = __builtin_amdgcn_cvt_pkrtz(dl9,  dl9);

    // cubic Taylor of exp(-x)
    const h2 C3 = {(__fp16)(-1.0f / 6.0f), (__fp16)(-1.0f / 6.0f)};
    const h2 C2 = {(__fp16)0.5f,  (__fp16)0.5f};
    const h2 C1 = {(__fp16)-1.0f, (__fp16)-1.0f};
    const h2 C0 = {(__fp16)1.0f,  (__fp16)1.0f};

    const float Rx = outc[(size_t)anchor * 3 + 0];
    const float Ry = outc[(size_t)anchor * 3 + 1];
    const float Rz = outc[(size_t)anchor * 3 + 2];

    f32x4 acc = {0.f, 0.f, 0.f, 0.f};

    const float* cb = coords + (size_t)b * NSRC * 3;
    const float* fb = f + (size_t)b * NSRC;

    // K-permuted write position (R25-verified): lane owns local srcs (2t,2t+1)
    const int t = lane & 15;
    const int pos = (t < 8) ? (8 * (t >> 1) + 2 * (t & 1))
                            : (8 * ((t - 8) >> 1) + 4 + 2 * (t & 1));
    const int whw = 32 * (lane >> 4) + pos;
    const int rhw = 8 * grp;

    for (int i = 0; i < 8; ++i) {             // 8 iterations, 128 src each
        const int s0 = w * (NSRC / 2) + i * 128 + 2 * lane;  // lane: s0, s0+1
        const float2 c0 = *(const float2*)(cb + (size_t)s0 * 3);      // x0 y0
        const float2 c1 = *(const float2*)(cb + (size_t)s0 * 3 + 2);  // z0 x1
        const float2 c2 = *(const float2*)(cb + (size_t)s0 * 3 + 4);  // y1 z1
        const float2 f2 = *(const float2*)(fb + s0);

        const float dx0 = c0.x - Rx, dy0 = c0.y - Ry, dz0 = c1.x - Rz;
        const float dx1 = c1.y - Rx, dy1 = c2.x - Ry, dz1 = c2.y - Rz;

        const float sq0 = dx0 * dx0 + dy0 * dy0 + dz0 * dz0;
        const float sq1 = dx1 * dx1 + dy1 * dy1 + dz1 * dz1;
        const float ri0 = __builtin_amdgcn_rsqf(sq0);
        const float ri1 = __builtin_amdgcn_rsqf(sq1);
        const float d0 = sq0 * ri0, d1 = sq1 * ri1;
        const float t0 = f2.x * ri0, t1 = f2.y * ri1;

        const h2 dpk = __builtin_amdgcn_cvt_pkrtz(d0, d1);

        h2 ep[16];
        ep[15] = __builtin_amdgcn_cvt_pkrtz(
            __builtin_amdgcn_exp2f(d0 * nm16), __builtin_amdgcn_exp2f(d1 * nm16));
        ep[13] = __builtin_amdgcn_cvt_pkrtz(
            __builtin_amdgcn_exp2f(d0 * nm14), __builtin_amdgcn_exp2f(d1 * nm14));
        ep[11] = __builtin_amdgcn_cvt_pkrtz(
            __builtin_amdgcn_exp2f(d0 * nm12), __builtin_amdgcn_exp2f(d1 * nm12));
        ep[9]  = __builtin_amdgcn_cvt_pkrtz(
            __builtin_amdgcn_exp2f(d0 * nm10), __builtin_amdgcn_exp2f(d1 * nm10));

        ep[7] = ep[15] * ep[15];   // E8
        ep[6] = ep[13] * ep[13];   // E7
        ep[5] = ep[11] * ep[11];   // E6
        ep[4] = ep[9]  * ep[9];    // E5
        ep[3] = ep[7]  * ep[7];    // E4
        ep[2] = ep[5]  * ep[5];    // E3
        ep[1] = ep[3]  * ep[3];    // E2
        ep[0] = ep[1]  * ep[1];    // E1

#define ODD(K_ODD, K_EVEN, HD)                                            \
        {                                                                 \
            h2 x = dpk * (HD);                                            \
            h2 p = C0 + x * (C1 + x * (C2 + x * C3));                     \
            ep[K_ODD] = ep[K_EVEN] * p;                                   \
        }
        ODD(14, 15, hD15)   // E15 = E16 * corr
        ODD(12, 13, hD13)   // E13 = E14 * corr
        ODD(10, 11, hD11)   // E11 = E12 * corr
        ODD(8,  9,  hD9)    // E9  = E10 * corr
#undef ODD

        // LDS scatter: one b32 per row (2 sources)
#pragma unroll
        for (int k = 0; k < 16; ++k)
            *(unsigned*)&eT[k][whw] = __builtin_bit_cast(unsigned, ep[k]);
        *(unsigned*)&wT[0][whw] =
            __builtin_bit_cast(unsigned, __builtin_amdgcn_cvt_pkrtz(f2.x, f2.y));
        *(unsigned*)&wT[1][whw] =
            __builtin_bit_cast(unsigned, __builtin_amdgcn_cvt_pkrtz(t0 * dx0, t1 * dx1));
        *(unsigned*)&wT[2][whw] =
            __builtin_bit_cast(unsigned, __builtin_amdgcn_cvt_pkrtz(t0 * dy0, t1 * dy1));
        *(unsigned*)&wT[3][whw] =
            __builtin_bit_cast(unsigned, __builtin_amdgcn_cvt_pkrtz(t0 * dz0, t1 * dz1));

        // 4 MFMA chunks of 32 sources, b128 fragment reads
#pragma unroll
        for (int c = 0; c < 4; ++c) {
            const f16x8 av = *(const f16x8*)&eT[col][32 * c + rhw];
            const f16x8 bv = *(const f16x8*)&wT[col & 3][32 * c + rhw];
            acc = __builtin_amdgcn_mfma_f32_16x16x32_f16(av, bv, acc, 0, 0, 0);
        }
    }

    // cross-wave combine: wave1 parks acc in its own (now dead) LDS region
    if (w == 1) {
        f32x4* red = (f32x4*)&sm[1][0][0];
        red[lane] = acc;
    }
    __syncthreads();
    if (w == 0) {
        const f32x4* red = (const f32x4*)&sm[1][0][0];
        acc += red[lane];
        // D[row=4*grp+r][col]: col = component, row = k (m89-verified map)
        if (col < 4) {
            const float4 r4 = *(const float4*)&rn[4 * grp];
            const float an = (col == 0) ? an0[0] : an1[0];
            float4 o;
            o.x = acc[0] * r4.x * an;
            o.y = acc[1] * r4.y * an;
            o.z = acc[2] * r4.z * an;
            o.w = acc[3] * r4.w * an;
            *(float4*)&out[(size_t)anchor * 64 + col * 16 + 4 * grp] = o;
        }
    }
}

extern "C" void kernel_launch(void* const* d_in, const int* in_sizes, int n_in,
                              void* d_out, int out_size, void* d_ws, size_t ws_size,
                              hipStream_t stream) {
    const float* f      = (const float*)d_in[0];
    const float* coords = (const float*)d_in[1];
    const float* outc   = (const float*)d_in[2];
    const float* mu     = (const float*)d_in[3];
    const float* rn     = (const float*)d_in[4];
    const float* an0    = (const float*)d_in[5];
    const float* an1    = (const float*)d_in[6];
    float* out = (float*)d_out;

    const int anchors = BATCH * MOUT;              // 4096 blocks, 2 waves each
    svp_kernel<<<anchors, 128, 0, stream>>>(f, coords, outc, mu, rn, an0, an1, out);
}

// Round 30
// 24.171 us; speedup vs baseline: 1.4177x; 1.0009x over previous
//
#include <hip/hip_runtime.h>

// SphericalVectorPool on MI355X — R25 + ds_write2_b32 packing (DS-pipe model).
// Model (fits R25 within 4%): CU-level DS occupancy = 20 write_b32 (~5.8cyc)
// + 8 read_b128 (~12cyc) = 212 cyc/wave-iter x 256 wave-iters/CU = 22.6us.
// This round halves the write count: rows k,k+1 are 272B (68 dwords) apart ->
// pairable into ds_write2_b32 (8 for eT + 2 for wT vs 20 singles). Emitted
// via inline asm on raw LDS offsets — valid because the ONLY shared alloc is
// extern __shared__ (dynamic LDS base = 0). Same-wave DS ops are in-order;
// "memory" clobber orders the compiler's fragment reads after the asm writes.
// E-gen, stride-136 layout (b128-read bank optimum, R28-proven), MFMA, D-map
// epilogue byte-identical to R25 (23.6us, absmax 0.09375).

constexpr int NR    = 16;
constexpr int BATCH = 2;
constexpr int NSRC  = 2048;
constexpr int MOUT  = 2048;

typedef __fp16 h2 __attribute__((ext_vector_type(2)));
typedef _Float16 f16x8 __attribute__((ext_vector_type(8)));
typedef float f32x4 __attribute__((ext_vector_type(4)));

// halfword geometry: wave tile = 20 rows x 136 hw; row stride 272B = 68 dwords
constexpr unsigned ROW_HW   = 136;
constexpr unsigned TILE_HW  = 20 * ROW_HW;            // 2720 hw = 5440 B
constexpr unsigned RED_OFF_HW = 2 * TILE_HW;          // red[] after both tiles
constexpr unsigned SMEM_BYTES = (2 * TILE_HW) * 2 + 64 * 16;  // 10880 + 1024

__global__ __launch_bounds__(128, 1) void svp_kernel(
    const float* __restrict__ f,       // [B,N]
    const float* __restrict__ coords,  // [B,N,3]
    const float* __restrict__ outc,    // [B,M,3]
    const float* __restrict__ mu,      // [16]
    const float* __restrict__ rn,      // [16]
    const float* __restrict__ an0,     // [1]
    const float* __restrict__ an1,     // [1]
    float* __restrict__ out)           // [B,M,64]
{
    extern __shared__ __align__(16) unsigned short smem[];

    const int tid  = threadIdx.x;
    const int lane = tid & 63;
    const int w    = tid >> 6;                // wave in block: 0..1
    const int anchor = blockIdx.x;            // 0..4095
    const int b = anchor >> 11;
    const int col = lane & 15;
    const int grp = lane >> 4;

    unsigned short* eTb = smem + w * TILE_HW;           // row k at + k*136
    unsigned short* wTb = eTb + 16 * ROW_HW;            // rows 16..19

    const float NL2E = -1.44269504088896340736f;

    const float nm16 = mu[15] * NL2E;
    const float nm14 = mu[13] * NL2E;
    const float nm12 = mu[11] * NL2E;
    const float nm10 = mu[9]  * NL2E;

    const float dl15 = mu[14] - mu[15];
    const float dl13 = mu[12] - mu[13];
    const float dl11 = mu[10] - mu[11];
    const float dl9  = mu[8]  - mu[9];
    const h2 hD15 = __builtin_amdgcn_cvt_pkrtz(dl15, dl15);
    const h2 hD13 = __builtin_amdgcn_cvt_pkrtz(dl13, dl13);
    const h2 hD11 = __builtin_amdgcn_cvt_pkrtz(dl11, dl11);
    const h2 hD9  = __builtin_amdgcn_cvt_pkrtz(dl9,  dl9);

    // cubic Taylor of exp(-x)
    const h2 C3 = {(__fp16)(-1.0f / 6.0f), (__fp16)(-1.0f / 6.0f)};
    const h2 C2 = {(__fp16)0.5f,  (__fp16)0.5f};
    const h2 C1 = {(__fp16)-1.0f, (__fp16)-1.0f};
    const h2 C0 = {(__fp16)1.0f,  (__fp16)1.0f};

    const float Rx = outc[(size_t)anchor * 3 + 0];
    const float Ry = outc[(size_t)anchor * 3 + 1];
    const float Rz = outc[(size_t)anchor * 3 + 2];

    f32x4 acc = {0.f, 0.f, 0.f, 0.f};

    const float* cb = coords + (size_t)b * NSRC * 3;
    const float* fb = f + (size_t)b * NSRC;

    // K-permuted write position (R25-verified): lane owns local srcs (2t,2t+1)
    const int t = lane & 15;
    const int pos = (t < 8) ? (8 * (t >> 1) + 2 * (t & 1))
                            : (8 * ((t - 8) >> 1) + 4 + 2 * (t & 1));
    const int whw = 32 * (lane >> 4) + pos;
    const int rhw = 8 * grp;

    // raw LDS byte offsets for the asm writes (dynamic-LDS base = 0)
    const unsigned tile_b = (unsigned)w * (TILE_HW * 2u);
    const unsigned e_b    = tile_b + (unsigned)(whw * 2);          // eT row 0
    const unsigned a0  = e_b;                // rows 0..3  (offsets 0,68,136,204)
    const unsigned a4  = e_b + 4 * 272u;     // rows 4..7
    const unsigned a8  = e_b + 8 * 272u;     // rows 8..11
    const unsigned a12 = e_b + 12 * 272u;    // rows 12..15
    const unsigned aw  = tile_b + 16 * 272u + (unsigned)(whw * 2); // wT row 0

#define W2A(addr, v0, v1)                                                 \
    asm volatile("ds_write2_b32 %0, %1, %2 offset0:0 offset1:68"          \
                 :: "v"(addr), "v"(v0), "v"(v1) : "memory");
#define W2B(addr, v0, v1)                                                 \
    asm volatile("ds_write2_b32 %0, %1, %2 offset0:136 offset1:204"       \
                 :: "v"(addr), "v"(v0), "v"(v1) : "memory");

    for (int i = 0; i < 8; ++i) {             // 8 iterations, 128 src each
        const int s0 = w * (NSRC / 2) + i * 128 + 2 * lane;  // lane: s0, s0+1
        const float2 c0 = *(const float2*)(cb + (size_t)s0 * 3);      // x0 y0
        const float2 c1 = *(const float2*)(cb + (size_t)s0 * 3 + 2);  // z0 x1
        const float2 c2 = *(const float2*)(cb + (size_t)s0 * 3 + 4);  // y1 z1
        const float2 f2 = *(const float2*)(fb + s0);

        const float dx0 = c0.x - Rx, dy0 = c0.y - Ry, dz0 = c1.x - Rz;
        const float dx1 = c1.y - Rx, dy1 = c2.x - Ry, dz1 = c2.y - Rz;

        const float sq0 = dx0 * dx0 + dy0 * dy0 + dz0 * dz0;
        const float sq1 = dx1 * dx1 + dy1 * dy1 + dz1 * dz1;
        const float ri0 = __builtin_amdgcn_rsqf(sq0);
        const float ri1 = __builtin_amdgcn_rsqf(sq1);
        const float d0 = sq0 * ri0, d1 = sq1 * ri1;
        const float t0 = f2.x * ri0, t1 = f2.y * ri1;

        const h2 dpk = __builtin_amdgcn_cvt_pkrtz(d0, d1);

        h2 ep[16];
        ep[15] = __builtin_amdgcn_cvt_pkrtz(
            __builtin_amdgcn_exp2f(d0 * nm16), __builtin_amdgcn_exp2f(d1 * nm16));
        ep[13] = __builtin_amdgcn_cvt_pkrtz(
            __builtin_amdgcn_exp2f(d0 * nm14), __builtin_amdgcn_exp2f(d1 * nm14));
        ep[11] = __builtin_amdgcn_cvt_pkrtz(
            __builtin_amdgcn_exp2f(d0 * nm12), __builtin_amdgcn_exp2f(d1 * nm12));
        ep[9]  = __builtin_amdgcn_cvt_pkrtz(
            __builtin_amdgcn_exp2f(d0 * nm10), __builtin_amdgcn_exp2f(d1 * nm10));

        ep[7] = ep[15] * ep[15];   // E8
        ep[6] = ep[13] * ep[13];   // E7
        ep[5] = ep[11] * ep[11];   // E6
        ep[4] = ep[9]  * ep[9];    // E5
        ep[3] = ep[7]  * ep[7];    // E4
        ep[2] = ep[5]  * ep[5];    // E3
        ep[1] = ep[3]  * ep[3];    // E2
        ep[0] = ep[1]  * ep[1];    // E1

#define ODD(K_ODD, K_EVEN, HD)                                            \
        {                                                                 \
            h2 x = dpk * (HD);                                            \
            h2 p = C0 + x * (C1 + x * (C2 + x * C3));                     \
            ep[K_ODD] = ep[K_EVEN] * p;                                   \
        }
        ODD(14, 15, hD15)   // E15 = E16 * corr
        ODD(12, 13, hD13)   // E13 = E14 * corr
        ODD(10, 11, hD11)   // E11 = E12 * corr
        ODD(8,  9,  hD9)    // E9  = E10 * corr
#undef ODD

        // LDS scatter: 10 ds_write2_b32 instead of 20 ds_write_b32
        unsigned u[16];
#pragma unroll
        for (int k = 0; k < 16; ++k) u[k] = __builtin_bit_cast(unsigned, ep[k]);
        W2A(a0,  u[0],  u[1])   W2B(a0,  u[2],  u[3])
        W2A(a4,  u[4],  u[5])   W2B(a4,  u[6],  u[7])
        W2A(a8,  u[8],  u[9])   W2B(a8,  u[10], u[11])
        W2A(a12, u[12], u[13])  W2B(a12, u[14], u[15])
        {
            const unsigned w0 = __builtin_bit_cast(unsigned, __builtin_amdgcn_cvt_pkrtz(f2.x, f2.y));
            const unsigned w1 = __builtin_bit_cast(unsigned, __builtin_amdgcn_cvt_pkrtz(t0 * dx0, t1 * dx1));
            const unsigned w2 = __builtin_bit_cast(unsigned, __builtin_amdgcn_cvt_pkrtz(t0 * dy0, t1 * dy1));
            const unsigned w3 = __builtin_bit_cast(unsigned, __builtin_amdgcn_cvt_pkrtz(t0 * dz0, t1 * dz1));
            W2A(aw, w0, w1)     W2B(aw, w2, w3)
        }
        // same-wave DS ops are in-order; "memory" clobber orders the
        // compiler's reads below after the asm writes above.

        // 4 MFMA chunks of 32 sources, b128 fragment reads
#pragma unroll
        for (int c = 0; c < 4; ++c) {
            const f16x8 av = *(const f16x8*)&eTb[col * ROW_HW + 32 * c + rhw];
            const f16x8 bv = *(const f16x8*)&wTb[(col & 3) * ROW_HW + 32 * c + rhw];
            acc = __builtin_amdgcn_mfma_f32_16x16x32_f16(av, bv, acc, 0, 0, 0);
        }
    }
#undef W2A
#undef W2B

    // cross-wave combine via red[] after both tiles
    f32x4* red = (f32x4*)(smem + RED_OFF_HW);
    if (w == 1) red[lane] = acc;
    __syncthreads();
    if (w == 0) {
        acc += red[lane];
        // D[row=4*grp+r][col]: col = component, row = k (m89-verified map)
        if (col < 4) {
            const float4 r4 = *(const float4*)&rn[4 * grp];
            const float an = (col == 0) ? an0[0] : an1[0];
            float4 o;
            o.x = acc[0] * r4.x * an;
            o.y = acc[1] * r4.y * an;
            o.z = acc[2] * r4.z * an;
            o.w = acc[3] * r4.w * an;
            *(float4*)&out[(size_t)anchor * 64 + col * 16 + 4 * grp] = o;
        }
    }
}

extern "C" void kernel_launch(void* const* d_in, const int* in_sizes, int n_in,
                              void* d_out, int out_size, void* d_ws, size_t ws_size,
                              hipStream_t stream) {
    const float* f      = (const float*)d_in[0];
    const float* coords = (const float*)d_in[1];
    const float* outc   = (const float*)d_in[2];
    const float* mu     = (const float*)d_in[3];
    const float* rn     = (const float*)d_in[4];
    const float* an0    = (const float*)d_in[5];
    const float* an1    = (const float*)d_in[6];
    float* out = (float*)d_out;

    const int anchors = BATCH * MOUT;              // 4096 blocks, 2 waves each
    svp_kernel<<<anchors, 128, SMEM_BYTES, stream>>>(f, coords, outc, mu, rn,
                                                     an0, an1, out);
}